// Round 2
// baseline (25885.501 us; speedup 1.0000x reference)
//
#include <hip/hip_runtime.h>
#include <math.h>

// Problem constants (EnhancedVectorQuantizer): inputs (16,4096,256) f32, emb (2048,256) f32
#define NROWS  65536
#define DIM    256
#define KCODES 2048

#define Q_OFF  16777216   // NROWS*DIM; d_out layout: [0,Q_OFF) quantized_st, [Q_OFF]=loss, [Q_OFF+1]=perplexity, [Q_OFF+2..) idx as f32

// workspace byte offsets
#define WS_C      0        // 2048 f32  ||e_k||^2
#define WS_INV    8192     // 2048 f32  1/max(rownorm,1e-12)
#define WS_COUNTS 16384    // 2048 u32
#define WS_SUMS   24576    // 3 doubles: [0]=mse_sum [1]=l2_sum [2]=orth_sum
#define WS_IDX    32768    // 65536 i32

// ---------------- init: zero accumulators (ws is poisoned 0xAA every launch) ----------------
__global__ void vq_init_kernel(unsigned* __restrict__ counts, double* __restrict__ sums) {
    int t = threadIdx.x;
    for (int k = t; k < KCODES; k += 256) counts[k] = 0u;
    if (t < 3) sums[t] = 0.0;
}

// ---------------- prep: c[k]=||e_k||^2, inv rownorm, l2 sum ----------------
__global__ void vq_prep_kernel(const float* __restrict__ emb, float* __restrict__ c,
                               float* __restrict__ invn, double* __restrict__ sums) {
    int k = blockIdx.x;
    int lane = threadIdx.x;                       // 64 lanes
    float4 v = ((const float4*)(emb + (size_t)k * DIM))[lane];
    float s = v.x * v.x + v.y * v.y + v.z * v.z + v.w * v.w;
    #pragma unroll
    for (int off = 32; off > 0; off >>= 1) s += __shfl_down(s, off, 64);
    if (lane == 0) {
        c[k] = s;
        float rn = sqrtf(s);
        invn[k] = 1.0f / fmaxf(rn, 1e-12f);
        atomicAdd(&sums[1], (double)rn);
    }
}

// ---------------- argmin: LDS-tiled fp32 distance GEMM + running argmin ----------------
// 256 threads (tx=tid&15 codes {tx+16i}, ty=tid>>4 rows {ty+16j}).
// BM=64 rows/block, BN=64 codes per kt tile, BK=64 dims per chunk.
// Single-buffered LDS chunks + register prefetch of next chunk (hides L2/LLC latency).
// 128 total steps = 32 kt-tiles x 4 d-chunks. LDS ~35KB -> 4 blocks/CU, grid 1024 = all resident.
#define BM 64
#define BN 64
#define BK 64
#define PAD 68   // 64+4: row stride 68 words -> both read patterns bank-optimal

__global__ __launch_bounds__(256, 4)
void vq_argmin_kernel(const float* __restrict__ x, const float* __restrict__ emb,
                      const float* __restrict__ c, int* __restrict__ idx_ws,
                      float* __restrict__ idx_f, unsigned* __restrict__ counts) {
    __shared__ float As[BM][PAD];
    __shared__ float Bs[BN][PAD];
    __shared__ float x2s[BM];

    const int tid = threadIdx.x;
    const int tx = tid & 15, ty = tid >> 4;
    const int row0 = blockIdx.x * BM;

    // per-row ||x||^2 — serial d=0..255, identical order/values to round 1 (which matched ref exactly)
    if (tid < BM) {
        const float* xr = x + (size_t)(row0 + tid) * DIM;
        float s = 0.f;
        for (int d = 0; d < DIM; ++d) { float a = xr[d]; s += a * a; }
        x2s[tid] = s;
    }

    const float4* x4 = (const float4*)x;
    const float4* e4 = (const float4*)emb;

    // stage step 0 (kt=0, dk=0) directly: each thread 4 float4 per tile
    #pragma unroll
    for (int q = 0; q < 4; ++q) {
        int r = 16 * q + ty;                     // local row
        float4 va = x4[(size_t)(row0 + r) * 64 + tx];
        float4 vb = e4[(size_t)r * 64 + tx];
        *(float4*)&As[r][tx << 2] = va;
        *(float4*)&Bs[r][tx << 2] = vb;
    }
    __syncthreads();

    float x2r[4];
    #pragma unroll
    for (int j = 0; j < 4; ++j) x2r[j] = x2s[ty + 16 * j];

    float best[4]; int bidx[4];
    #pragma unroll
    for (int j = 0; j < 4; ++j) { best[j] = 3.4e38f; bidx[j] = 0; }

    float acc[4][4];
    #pragma unroll
    for (int j = 0; j < 4; ++j)
        #pragma unroll
        for (int i = 0; i < 4; ++i) acc[j][i] = 0.f;

    for (int s = 0; s < 128; ++s) {
        // prefetch step s+1 (wraps at end; last prefetch unused)
        int sn = (s + 1) & 127;
        int dkn4 = (sn & 3) << 4;                // d-chunk offset in float4 units
        int ktn  = (sn >> 2) << 6;
        float4 pA[4], pB[4];
        #pragma unroll
        for (int q = 0; q < 4; ++q) {
            int r = 16 * q + ty;
            pA[q] = x4[(size_t)(row0 + r) * 64 + dkn4 + tx];
            pB[q] = e4[(size_t)(ktn  + r) * 64 + dkn4 + tx];
        }

        // compute: acc[j][i] += x_row(j) . e_code(i) over this 64-dim chunk
        #pragma unroll
        for (int dd = 0; dd < BK; dd += 4) {
            float4 a[4], b[4];
            #pragma unroll
            for (int j = 0; j < 4; ++j) a[j] = *(const float4*)&As[ty + 16 * j][dd];
            #pragma unroll
            for (int i = 0; i < 4; ++i) b[i] = *(const float4*)&Bs[tx + 16 * i][dd];
            #pragma unroll
            for (int j = 0; j < 4; ++j)
                #pragma unroll
                for (int i = 0; i < 4; ++i)
                    acc[j][i] += a[j].x * b[i].x + a[j].y * b[i].y
                               + a[j].z * b[i].z + a[j].w * b[i].w;
        }

        if ((s & 3) == 3) {                      // full D done for this kt tile: fold argmin
            int kt = (s >> 2) << 6;
            #pragma unroll
            for (int i = 0; i < 4; ++i) {
                int k = kt + tx + 16 * i;        // ascending in i -> lowest-index tie win
                float ck = c[k];
                #pragma unroll
                for (int j = 0; j < 4; ++j) {
                    float t = x2r[j] + ck;               // matches reference eval order
                    float dst = t - 2.0f * acc[j][i];    // *2 exact
                    if (dst < best[j]) { best[j] = dst; bidx[j] = k; }
                }
            }
            #pragma unroll
            for (int j = 0; j < 4; ++j)
                #pragma unroll
                for (int i = 0; i < 4; ++i) acc[j][i] = 0.f;
        }

        __syncthreads();                         // all waves done reading this chunk
        if (s < 127) {
            #pragma unroll
            for (int q = 0; q < 4; ++q) {
                int r = 16 * q + ty;
                *(float4*)&As[r][tx << 2] = pA[q];
                *(float4*)&Bs[r][tx << 2] = pB[q];
            }
        }
        __syncthreads();                         // chunk s+1 visible
    }

    // final reduction: reuse As/Bs as redv/redi (all compute reads are behind the last barrier)
    float* redv = &As[0][0];                     // [64][16]
    int*   redi = (int*)&Bs[0][0];
    #pragma unroll
    for (int j = 0; j < 4; ++j) {
        int r = ty + 16 * j;
        redv[r * 16 + tx] = best[j];
        redi[r * 16 + tx] = bidx[j];
    }
    __syncthreads();
    if (tid < BM) {
        float bv = redv[tid * 16]; int bi = redi[tid * 16];
        for (int t = 1; t < 16; ++t) {
            float v = redv[tid * 16 + t]; int ii = redi[tid * 16 + t];
            if (v < bv || (v == bv && ii < bi)) { bv = v; bi = ii; }  // ties -> lowest index
        }
        int n = row0 + tid;
        idx_ws[n] = bi;
        idx_f[n] = (float)bi;
        atomicAdd(&counts[bi], 1u);
    }
}

// ---------------- gather: quantized_st = x + (e - x) (matches ST rounding), MSE sum ----------------
__global__ void vq_gather_kernel(const float* __restrict__ x, const float* __restrict__ emb,
                                 const int* __restrict__ idx, float* __restrict__ outq,
                                 double* __restrict__ sums) {
    __shared__ float red[256];
    int tid = threadIdx.x;
    int q = blockIdx.x * 256 + tid;        // float4 index, 4194304 total
    int n = q >> 6;
    int d4 = (q & 63) << 2;
    int k = idx[n];
    float4 e  = *(const float4*)(emb + (size_t)k * DIM + d4);
    float4 xv = *(const float4*)(x + ((size_t)n * DIM + d4));
    float d0 = e.x - xv.x, d1 = e.y - xv.y, d2 = e.z - xv.z, d3 = e.w - xv.w;
    float4 o;
    o.x = xv.x + d0; o.y = xv.y + d1; o.z = xv.z + d2; o.w = xv.w + d3;
    *(float4*)(outq + (size_t)q * 4) = o;
    red[tid] = d0 * d0 + d1 * d1 + d2 * d2 + d3 * d3;
    __syncthreads();
    for (int off = 128; off > 0; off >>= 1) {
        if (tid < off) red[tid] += red[tid + off];
        __syncthreads();
    }
    if (tid == 0) atomicAdd(&sums[0], (double)red[0]);
}

// ---------------- sim: sum |off-diagonal cosine| ----------------
#define SPAD 68
__global__ __launch_bounds__(256)
void vq_sim_kernel(const float* __restrict__ emb, const float* __restrict__ invn,
                   double* __restrict__ sums) {
    __shared__ float Ai[64][SPAD];
    __shared__ float Bj[64][SPAD];
    int bi = blockIdx.x >> 5;
    int bj = blockIdx.x & 31;
    int tid = threadIdx.x;
    int tx = tid & 15, ty = tid >> 4;

    float acc[4][4];
    #pragma unroll
    for (int j = 0; j < 4; ++j)
        #pragma unroll
        for (int i = 0; i < 4; ++i) acc[j][i] = 0.f;

    for (int dc = 0; dc < DIM; dc += 64) {
        #pragma unroll
        for (int rr = 0; rr < 4; ++rr) {
            int row = rr * 16 + ty;
            int col = tx * 4;
            int ga = bi * 64 + row, gb = bj * 64 + row;
            float4 a = *(const float4*)(emb + (size_t)ga * DIM + dc + col);
            float4 b = *(const float4*)(emb + (size_t)gb * DIM + dc + col);
            float sa = invn[ga], sb = invn[gb];
            Ai[row][col + 0] = a.x * sa; Ai[row][col + 1] = a.y * sa;
            Ai[row][col + 2] = a.z * sa; Ai[row][col + 3] = a.w * sa;
            Bj[row][col + 0] = b.x * sb; Bj[row][col + 1] = b.y * sb;
            Bj[row][col + 2] = b.z * sb; Bj[row][col + 3] = b.w * sb;
        }
        __syncthreads();
        for (int d = 0; d < 64; d += 4) {
            float4 a[4], b[4];
            #pragma unroll
            for (int j = 0; j < 4; ++j) a[j] = *(const float4*)&Ai[ty * 4 + j][d];
            #pragma unroll
            for (int i = 0; i < 4; ++i) b[i] = *(const float4*)&Bj[tx * 4 + i][d];
            #pragma unroll
            for (int j = 0; j < 4; ++j)
                #pragma unroll
                for (int i = 0; i < 4; ++i)
                    acc[j][i] += a[j].x * b[i].x + a[j].y * b[i].y
                               + a[j].z * b[i].z + a[j].w * b[i].w;
        }
        __syncthreads();
    }
    float s = 0.f;
    #pragma unroll
    for (int j = 0; j < 4; ++j)
        #pragma unroll
        for (int i = 0; i < 4; ++i) {
            int gi = bi * 64 + ty * 4 + j;
            int gj = bj * 64 + tx * 4 + i;
            if (gi != gj) s += fabsf(acc[j][i]);
        }
    float* red = &Ai[0][0];
    red[tid] = s;
    __syncthreads();
    for (int off = 128; off > 0; off >>= 1) {
        if (tid < off) red[tid] += red[tid + off];
        __syncthreads();
    }
    if (tid == 0) atomicAdd(&sums[2], (double)red[0]);
}

// ---------------- finalize: KL, perplexity, total loss ----------------
__global__ void vq_finalize_kernel(const unsigned* __restrict__ counts,
                                   const double* __restrict__ sums,
                                   float* __restrict__ out_scalars) {
    __shared__ double sred[256];
    int tid = threadIdx.x;
    double t = 0.0;
    for (int k = tid; k < KCODES; k += 256) t += (double)counts[k];
    sred[tid] = t; __syncthreads();
    for (int off = 128; off > 0; off >>= 1) {
        if (tid < off) sred[tid] += sred[tid + off];
        __syncthreads();
    }
    double total = sred[0];
    __syncthreads();

    const double eps = 1e-8, tunif = 1.0 / (double)KCODES;
    double klsum = 0.0, plogpsum = 0.0;
    for (int k = tid; k < KCODES; k += 256) {
        double p = (double)counts[k] / total;
        klsum += (p + eps) * log((p + eps) / (tunif + eps));
        if (p > 0.0) plogpsum += p * log(p);
    }
    sred[tid] = klsum; __syncthreads();
    for (int off = 128; off > 0; off >>= 1) {
        if (tid < off) sred[tid] += sred[tid + off];
        __syncthreads();
    }
    klsum = sred[0];
    __syncthreads();
    sred[tid] = plogpsum; __syncthreads();
    for (int off = 128; off > 0; off >>= 1) {
        if (tid < off) sred[tid] += sred[tid + off];
        __syncthreads();
    }
    plogpsum = sred[0];

    if (tid == 0) {
        float mse = (float)(sums[0] / (double)((size_t)NROWS * DIM));
        float vq = mse + 0.25f * mse;                       // q_latent + COST*e_latent (equal in value)
        float kl = fminf((float)klsum, 100.0f);
        float l2 = fminf((float)(sums[1] / (double)KCODES), 10.0f);
        float orth = fminf((float)(sums[2] / ((double)KCODES * (double)KCODES)), 10.0f);
        float reg = l2 + orth;
        float total_loss = fminf(vq + 0.1f * kl + 0.01f * reg, 100.0f);
        out_scalars[0] = total_loss;
        out_scalars[1] = (float)exp(-plogpsum);
    }
}

extern "C" void kernel_launch(void* const* d_in, const int* in_sizes, int n_in,
                              void* d_out, int out_size, void* d_ws, size_t ws_size,
                              hipStream_t stream) {
    const float* x   = (const float*)d_in[0];   // (16,4096,256) f32
    const float* emb = (const float*)d_in[1];   // (2048,256)   f32
    float* out = (float*)d_out;

    char* ws = (char*)d_ws;
    float*    c      = (float*)(ws + WS_C);
    float*    invn   = (float*)(ws + WS_INV);
    unsigned* counts = (unsigned*)(ws + WS_COUNTS);
    double*   sums   = (double*)(ws + WS_SUMS);
    int*      idx_ws = (int*)(ws + WS_IDX);

    float* outq        = out;                 // quantized_st
    float* out_scalars = out + Q_OFF;         // loss, perplexity
    float* idx_f       = out + Q_OFF + 2;     // idx as float

    vq_init_kernel<<<1, 256, 0, stream>>>(counts, sums);
    vq_prep_kernel<<<KCODES, 64, 0, stream>>>(emb, c, invn, sums);
    vq_argmin_kernel<<<NROWS / BM, 256, 0, stream>>>(x, emb, c, idx_ws, idx_f, counts);
    vq_gather_kernel<<<(NROWS * DIM / 4) / 256, 256, 0, stream>>>(x, emb, idx_ws, outq, sums);
    vq_sim_kernel<<<(KCODES / 64) * (KCODES / 64), 256, 0, stream>>>(emb, invn, sums);
    vq_finalize_kernel<<<1, 256, 0, stream>>>(counts, sums, out_scalars);
}

// Round 3
// 2332.430 us; speedup vs baseline: 11.0981x; 11.0981x over previous
//
#include <hip/hip_runtime.h>
#include <math.h>

// Problem constants (EnhancedVectorQuantizer): inputs (16,4096,256) f32, emb (2048,256) f32
#define NROWS  65536
#define DIM    256
#define KCODES 2048

#define Q_OFF  16777216   // NROWS*DIM; d_out layout: [0,Q_OFF) quantized_st, [Q_OFF]=loss, [Q_OFF+1]=perplexity, [Q_OFF+2..) idx as f32

// workspace byte offsets
#define WS_C      0        // 2048 f32  ||e_k||^2
#define WS_INV    8192     // 2048 f32  1/max(rownorm,1e-12)
#define WS_COUNTS 16384    // 2048 u32
#define WS_SUMS   24576    // 3 doubles: [0]=mse_sum [1]=l2_sum [2]=orth_sum
#define WS_IDX    32768    // 65536 i32

// ---------------- init: zero accumulators (ws is poisoned 0xAA every launch) ----------------
__global__ void vq_init_kernel(unsigned* __restrict__ counts, double* __restrict__ sums) {
    int t = threadIdx.x;
    for (int k = t; k < KCODES; k += 256) counts[k] = 0u;
    if (t < 3) sums[t] = 0.0;
}

// ---------------- prep: c[k]=||e_k||^2, inv rownorm, l2 sum ----------------
__global__ void vq_prep_kernel(const float* __restrict__ emb, float* __restrict__ c,
                               float* __restrict__ invn, double* __restrict__ sums) {
    int k = blockIdx.x;
    int lane = threadIdx.x;                       // 64 lanes
    float4 v = ((const float4*)(emb + (size_t)k * DIM))[lane];
    float s = v.x * v.x + v.y * v.y + v.z * v.z + v.w * v.w;
    #pragma unroll
    for (int off = 32; off > 0; off >>= 1) s += __shfl_down(s, off, 64);
    if (lane == 0) {
        c[k] = s;
        float rn = sqrtf(s);
        invn[k] = 1.0f / fmaxf(rn, 1e-12f);
        atomicAdd(&sums[1], (double)rn);
    }
}

// ---------------- argmin: LDS-tiled fp32 distance GEMM + running argmin ----------------
// 256 threads (tx=tid&15 codes {tx+16i}, ty=tid>>4 rows {ty+16j}).
// BM=64 rows/block, BN=64 codes per kt tile, BK=64 dims per chunk.
// Single-buffered LDS chunks + register prefetch of next chunk (hides L2/LLC latency).
// 128 total steps = 32 kt-tiles x 4 d-chunks.
// __launch_bounds__(256,2): cap 256 VGPR. (256,4) capped at 128 and spilled 93 GB
// of scratch traffic (round 2: 25.5 ms, FETCH 36 GB / WRITE 54 GB). ~130-160 VGPR
// live here -> 3 waves/SIMD, no spill.
#define BM 64
#define BN 64
#define BK 64
#define PAD 68   // 64+4: row stride 68 words -> both read patterns bank-optimal

__global__ __launch_bounds__(256, 2)
void vq_argmin_kernel(const float* __restrict__ x, const float* __restrict__ emb,
                      const float* __restrict__ c, int* __restrict__ idx_ws,
                      float* __restrict__ idx_f, unsigned* __restrict__ counts) {
    __shared__ float As[BM][PAD];
    __shared__ float Bs[BN][PAD];
    __shared__ float x2s[BM];

    const int tid = threadIdx.x;
    const int tx = tid & 15, ty = tid >> 4;
    const int row0 = blockIdx.x * BM;

    // per-row ||x||^2 — float4 loads, serial component adds: identical rounding
    // chain to the scalar d=0..255 loop that matched the reference exactly.
    if (tid < BM) {
        const float4* xr = (const float4*)(x + (size_t)(row0 + tid) * DIM);
        float s = 0.f;
        for (int d4 = 0; d4 < DIM / 4; ++d4) {
            float4 v = xr[d4];
            s += v.x * v.x; s += v.y * v.y; s += v.z * v.z; s += v.w * v.w;
        }
        x2s[tid] = s;
    }

    const float4* x4 = (const float4*)x;
    const float4* e4 = (const float4*)emb;

    // stage step 0 (kt=0, dk=0) directly: each thread 4 float4 per tile
    #pragma unroll
    for (int q = 0; q < 4; ++q) {
        int r = 16 * q + ty;                     // local row
        float4 va = x4[(size_t)(row0 + r) * 64 + tx];
        float4 vb = e4[(size_t)r * 64 + tx];
        *(float4*)&As[r][tx << 2] = va;
        *(float4*)&Bs[r][tx << 2] = vb;
    }
    __syncthreads();

    float x2r[4];
    #pragma unroll
    for (int j = 0; j < 4; ++j) x2r[j] = x2s[ty + 16 * j];

    float best[4]; int bidx[4];
    #pragma unroll
    for (int j = 0; j < 4; ++j) { best[j] = 3.4e38f; bidx[j] = 0; }

    float acc[4][4];
    #pragma unroll
    for (int j = 0; j < 4; ++j)
        #pragma unroll
        for (int i = 0; i < 4; ++i) acc[j][i] = 0.f;

    for (int s = 0; s < 128; ++s) {
        // prefetch step s+1 (wraps at end; last prefetch unused)
        int sn = (s + 1) & 127;
        int dkn4 = (sn & 3) << 4;                // d-chunk offset in float4 units
        int ktn  = (sn >> 2) << 6;
        float4 pA[4], pB[4];
        #pragma unroll
        for (int q = 0; q < 4; ++q) {
            int r = 16 * q + ty;
            pA[q] = x4[(size_t)(row0 + r) * 64 + dkn4 + tx];
            pB[q] = e4[(size_t)(ktn  + r) * 64 + dkn4 + tx];
        }

        // compute: acc[j][i] += x_row(j) . e_code(i) over this 64-dim chunk
        #pragma unroll
        for (int dd = 0; dd < BK; dd += 4) {
            float4 a[4], b[4];
            #pragma unroll
            for (int j = 0; j < 4; ++j) a[j] = *(const float4*)&As[ty + 16 * j][dd];
            #pragma unroll
            for (int i = 0; i < 4; ++i) b[i] = *(const float4*)&Bs[tx + 16 * i][dd];
            #pragma unroll
            for (int j = 0; j < 4; ++j)
                #pragma unroll
                for (int i = 0; i < 4; ++i)
                    acc[j][i] += a[j].x * b[i].x + a[j].y * b[i].y
                               + a[j].z * b[i].z + a[j].w * b[i].w;
        }

        if ((s & 3) == 3) {                      // full D done for this kt tile: fold argmin
            int kt = (s >> 2) << 6;
            #pragma unroll
            for (int i = 0; i < 4; ++i) {
                int k = kt + tx + 16 * i;        // ascending in i -> lowest-index tie win
                float ck = c[k];
                #pragma unroll
                for (int j = 0; j < 4; ++j) {
                    float t = x2r[j] + ck;               // matches reference eval order
                    float dst = t - 2.0f * acc[j][i];    // *2 exact
                    if (dst < best[j]) { best[j] = dst; bidx[j] = k; }
                }
            }
            #pragma unroll
            for (int j = 0; j < 4; ++j)
                #pragma unroll
                for (int i = 0; i < 4; ++i) acc[j][i] = 0.f;
        }

        __syncthreads();                         // all waves done reading this chunk
        if (s < 127) {
            #pragma unroll
            for (int q = 0; q < 4; ++q) {
                int r = 16 * q + ty;
                *(float4*)&As[r][tx << 2] = pA[q];
                *(float4*)&Bs[r][tx << 2] = pB[q];
            }
        }
        __syncthreads();                         // chunk s+1 visible
    }

    // final reduction: reuse As/Bs as redv/redi (all compute reads are behind the last barrier)
    float* redv = &As[0][0];                     // [64][16]
    int*   redi = (int*)&Bs[0][0];
    #pragma unroll
    for (int j = 0; j < 4; ++j) {
        int r = ty + 16 * j;
        redv[r * 16 + tx] = best[j];
        redi[r * 16 + tx] = bidx[j];
    }
    __syncthreads();
    if (tid < BM) {
        float bv = redv[tid * 16]; int bi = redi[tid * 16];
        for (int t = 1; t < 16; ++t) {
            float v = redv[tid * 16 + t]; int ii = redi[tid * 16 + t];
            if (v < bv || (v == bv && ii < bi)) { bv = v; bi = ii; }  // ties -> lowest index
        }
        int n = row0 + tid;
        idx_ws[n] = bi;
        idx_f[n] = (float)bi;
        atomicAdd(&counts[bi], 1u);
    }
}

// ---------------- gather: quantized_st = x + (e - x) (matches ST rounding), MSE sum ----------------
__global__ void vq_gather_kernel(const float* __restrict__ x, const float* __restrict__ emb,
                                 const int* __restrict__ idx, float* __restrict__ outq,
                                 double* __restrict__ sums) {
    __shared__ float red[256];
    int tid = threadIdx.x;
    int q = blockIdx.x * 256 + tid;        // float4 index, 4194304 total
    int n = q >> 6;
    int d4 = (q & 63) << 2;
    int k = idx[n];
    float4 e  = *(const float4*)(emb + (size_t)k * DIM + d4);
    float4 xv = *(const float4*)(x + ((size_t)n * DIM + d4));
    float d0 = e.x - xv.x, d1 = e.y - xv.y, d2 = e.z - xv.z, d3 = e.w - xv.w;
    float4 o;
    o.x = xv.x + d0; o.y = xv.y + d1; o.z = xv.z + d2; o.w = xv.w + d3;
    *(float4*)(outq + (size_t)q * 4) = o;
    red[tid] = d0 * d0 + d1 * d1 + d2 * d2 + d3 * d3;
    __syncthreads();
    for (int off = 128; off > 0; off >>= 1) {
        if (tid < off) red[tid] += red[tid + off];
        __syncthreads();
    }
    if (tid == 0) atomicAdd(&sums[0], (double)red[0]);
}

// ---------------- sim: sum |off-diagonal cosine| ----------------
#define SPAD 68
__global__ __launch_bounds__(256)
void vq_sim_kernel(const float* __restrict__ emb, const float* __restrict__ invn,
                   double* __restrict__ sums) {
    __shared__ float Ai[64][SPAD];
    __shared__ float Bj[64][SPAD];
    int bi = blockIdx.x >> 5;
    int bj = blockIdx.x & 31;
    int tid = threadIdx.x;
    int tx = tid & 15, ty = tid >> 4;

    float acc[4][4];
    #pragma unroll
    for (int j = 0; j < 4; ++j)
        #pragma unroll
        for (int i = 0; i < 4; ++i) acc[j][i] = 0.f;

    for (int dc = 0; dc < DIM; dc += 64) {
        #pragma unroll
        for (int rr = 0; rr < 4; ++rr) {
            int row = rr * 16 + ty;
            int col = tx * 4;
            int ga = bi * 64 + row, gb = bj * 64 + row;
            float4 a = *(const float4*)(emb + (size_t)ga * DIM + dc + col);
            float4 b = *(const float4*)(emb + (size_t)gb * DIM + dc + col);
            float sa = invn[ga], sb = invn[gb];
            Ai[row][col + 0] = a.x * sa; Ai[row][col + 1] = a.y * sa;
            Ai[row][col + 2] = a.z * sa; Ai[row][col + 3] = a.w * sa;
            Bj[row][col + 0] = b.x * sb; Bj[row][col + 1] = b.y * sb;
            Bj[row][col + 2] = b.z * sb; Bj[row][col + 3] = b.w * sb;
        }
        __syncthreads();
        for (int d = 0; d < 64; d += 4) {
            float4 a[4], b[4];
            #pragma unroll
            for (int j = 0; j < 4; ++j) a[j] = *(const float4*)&Ai[ty * 4 + j][d];
            #pragma unroll
            for (int i = 0; i < 4; ++i) b[i] = *(const float4*)&Bj[tx * 4 + i][d];
            #pragma unroll
            for (int j = 0; j < 4; ++j)
                #pragma unroll
                for (int i = 0; i < 4; ++i)
                    acc[j][i] += a[j].x * b[i].x + a[j].y * b[i].y
                               + a[j].z * b[i].z + a[j].w * b[i].w;
        }
        __syncthreads();
    }
    float s = 0.f;
    #pragma unroll
    for (int j = 0; j < 4; ++j)
        #pragma unroll
        for (int i = 0; i < 4; ++i) {
            int gi = bi * 64 + ty * 4 + j;
            int gj = bj * 64 + tx * 4 + i;
            if (gi != gj) s += fabsf(acc[j][i]);
        }
    float* red = &Ai[0][0];
    red[tid] = s;
    __syncthreads();
    for (int off = 128; off > 0; off >>= 1) {
        if (tid < off) red[tid] += red[tid + off];
        __syncthreads();
    }
    if (tid == 0) atomicAdd(&sums[2], (double)red[0]);
}

// ---------------- finalize: KL, perplexity, total loss ----------------
__global__ void vq_finalize_kernel(const unsigned* __restrict__ counts,
                                   const double* __restrict__ sums,
                                   float* __restrict__ out_scalars) {
    __shared__ double sred[256];
    int tid = threadIdx.x;
    double t = 0.0;
    for (int k = tid; k < KCODES; k += 256) t += (double)counts[k];
    sred[tid] = t; __syncthreads();
    for (int off = 128; off > 0; off >>= 1) {
        if (tid < off) sred[tid] += sred[tid + off];
        __syncthreads();
    }
    double total = sred[0];
    __syncthreads();

    const double eps = 1e-8, tunif = 1.0 / (double)KCODES;
    double klsum = 0.0, plogpsum = 0.0;
    for (int k = tid; k < KCODES; k += 256) {
        double p = (double)counts[k] / total;
        klsum += (p + eps) * log((p + eps) / (tunif + eps));
        if (p > 0.0) plogpsum += p * log(p);
    }
    sred[tid] = klsum; __syncthreads();
    for (int off = 128; off > 0; off >>= 1) {
        if (tid < off) sred[tid] += sred[tid + off];
        __syncthreads();
    }
    klsum = sred[0];
    __syncthreads();
    sred[tid] = plogpsum; __syncthreads();
    for (int off = 128; off > 0; off >>= 1) {
        if (tid < off) sred[tid] += sred[tid + off];
        __syncthreads();
    }
    plogpsum = sred[0];

    if (tid == 0) {
        float mse = (float)(sums[0] / (double)((size_t)NROWS * DIM));
        float vq = mse + 0.25f * mse;                       // q_latent + COST*e_latent (equal in value)
        float kl = fminf((float)klsum, 100.0f);
        float l2 = fminf((float)(sums[1] / (double)KCODES), 10.0f);
        float orth = fminf((float)(sums[2] / ((double)KCODES * (double)KCODES)), 10.0f);
        float reg = l2 + orth;
        float total_loss = fminf(vq + 0.1f * kl + 0.01f * reg, 100.0f);
        out_scalars[0] = total_loss;
        out_scalars[1] = (float)exp(-plogpsum);
    }
}

extern "C" void kernel_launch(void* const* d_in, const int* in_sizes, int n_in,
                              void* d_out, int out_size, void* d_ws, size_t ws_size,
                              hipStream_t stream) {
    const float* x   = (const float*)d_in[0];   // (16,4096,256) f32
    const float* emb = (const float*)d_in[1];   // (2048,256)   f32
    float* out = (float*)d_out;

    char* ws = (char*)d_ws;
    float*    c      = (float*)(ws + WS_C);
    float*    invn   = (float*)(ws + WS_INV);
    unsigned* counts = (unsigned*)(ws + WS_COUNTS);
    double*   sums   = (double*)(ws + WS_SUMS);
    int*      idx_ws = (int*)(ws + WS_IDX);

    float* outq        = out;                 // quantized_st
    float* out_scalars = out + Q_OFF;         // loss, perplexity
    float* idx_f       = out + Q_OFF + 2;     // idx as float

    vq_init_kernel<<<1, 256, 0, stream>>>(counts, sums);
    vq_prep_kernel<<<KCODES, 64, 0, stream>>>(emb, c, invn, sums);
    vq_argmin_kernel<<<NROWS / BM, 256, 0, stream>>>(x, emb, c, idx_ws, idx_f, counts);
    vq_gather_kernel<<<(NROWS * DIM / 4) / 256, 256, 0, stream>>>(x, emb, idx_ws, outq, sums);
    vq_sim_kernel<<<(KCODES / 64) * (KCODES / 64), 256, 0, stream>>>(emb, invn, sums);
    vq_finalize_kernel<<<1, 256, 0, stream>>>(counts, sums, out_scalars);
}

// Round 4
// 1953.193 us; speedup vs baseline: 13.2529x; 1.1942x over previous
//
#include <hip/hip_runtime.h>
#include <math.h>

// Problem constants (EnhancedVectorQuantizer): inputs (16,4096,256) f32, emb (2048,256) f32
#define NROWS  65536
#define DIM    256
#define KCODES 2048

#define Q_OFF  16777216   // NROWS*DIM; d_out layout: [0,Q_OFF) quantized_st, [Q_OFF]=loss, [Q_OFF+1]=perplexity, [Q_OFF+2..) idx as f32

// workspace byte offsets
#define WS_C      0        // 2048 f32  ||e_k||^2
#define WS_INV    8192     // 2048 f32  1/max(rownorm,1e-12)
#define WS_COUNTS 16384    // 2048 u32
#define WS_SUMS   24576    // 3 doubles: [0]=mse_sum [1]=l2_sum [2]=orth_sum
#define WS_IDX    32768    // 65536 i32

// ---------------- init: zero accumulators (ws is poisoned 0xAA every launch) ----------------
__global__ void vq_init_kernel(unsigned* __restrict__ counts, double* __restrict__ sums) {
    int t = threadIdx.x;
    for (int k = t; k < KCODES; k += 256) counts[k] = 0u;
    if (t < 3) sums[t] = 0.0;
}

// ---------------- prep: c[k]=||e_k||^2, inv rownorm, l2 sum ----------------
__global__ void vq_prep_kernel(const float* __restrict__ emb, float* __restrict__ c,
                               float* __restrict__ invn, double* __restrict__ sums) {
    int k = blockIdx.x;
    int lane = threadIdx.x;                       // 64 lanes
    float4 v = ((const float4*)(emb + (size_t)k * DIM))[lane];
    float s = v.x * v.x + v.y * v.y + v.z * v.z + v.w * v.w;
    #pragma unroll
    for (int off = 32; off > 0; off >>= 1) s += __shfl_down(s, off, 64);
    if (lane == 0) {
        c[k] = s;
        float rn = sqrtf(s);
        invn[k] = 1.0f / fmaxf(rn, 1e-12f);
        atomicAdd(&sums[1], (double)rn);
    }
}

// ---------------- argmin: LDS-tiled fp32 distance GEMM + running argmin ----------------
// 256 threads (tx=tid&15 codes {tx+16i}, ty=tid>>4 rows {ty+16j}).
// BM=64 rows/block, BN=64 codes per kt tile, BK=64 dims per chunk.
// Single-buffered LDS chunks + register prefetch of next chunk (hides L2/LLC latency).
// 128 total steps = 32 kt-tiles x 4 d-chunks.
//
// Register-allocation history:
//   (256,4): cap 128, allocator chose 64  -> 93 GB scratch spill, 25.5 ms
//   (256,2): cap 256, allocator chose 128 -> 3.7 GB spill (the 32-reg prefetch), 2.2 ms
// The allocator targets cap/2 to gain +1 wave of occupancy, accepting spill.
// amdgpu_waves_per_eu(2,2) pins occupancy at exactly 2 waves/EU: no incentive to
// allocate below 256 regs -> prefetch stays in registers, no spill.
#define BM 64
#define BN 64
#define BK 64
#define PAD 68   // 64+4: row stride 68 words -> both read patterns bank-optimal

__global__ __launch_bounds__(256)
__attribute__((amdgpu_waves_per_eu(2, 2)))
void vq_argmin_kernel(const float* __restrict__ x, const float* __restrict__ emb,
                      const float* __restrict__ c, int* __restrict__ idx_ws,
                      float* __restrict__ idx_f, unsigned* __restrict__ counts) {
    __shared__ float As[BM][PAD];
    __shared__ float Bs[BN][PAD];
    __shared__ float x2s[BM];

    const int tid = threadIdx.x;
    const int tx = tid & 15, ty = tid >> 4;
    const int row0 = blockIdx.x * BM;

    // per-row ||x||^2 — float4 loads, serial component adds: identical rounding
    // chain to the scalar d=0..255 loop that matched the reference exactly.
    if (tid < BM) {
        const float4* xr = (const float4*)(x + (size_t)(row0 + tid) * DIM);
        float s = 0.f;
        for (int d4 = 0; d4 < DIM / 4; ++d4) {
            float4 v = xr[d4];
            s += v.x * v.x; s += v.y * v.y; s += v.z * v.z; s += v.w * v.w;
        }
        x2s[tid] = s;
    }

    const float4* x4 = (const float4*)x;
    const float4* e4 = (const float4*)emb;

    // stage step 0 (kt=0, dk=0) directly: each thread 4 float4 per tile
    #pragma unroll
    for (int q = 0; q < 4; ++q) {
        int r = 16 * q + ty;                     // local row
        float4 va = x4[(size_t)(row0 + r) * 64 + tx];
        float4 vb = e4[(size_t)r * 64 + tx];
        *(float4*)&As[r][tx << 2] = va;
        *(float4*)&Bs[r][tx << 2] = vb;
    }
    __syncthreads();

    float x2r[4];
    #pragma unroll
    for (int j = 0; j < 4; ++j) x2r[j] = x2s[ty + 16 * j];

    float best[4]; int bidx[4];
    #pragma unroll
    for (int j = 0; j < 4; ++j) { best[j] = 3.4e38f; bidx[j] = 0; }

    float acc[4][4];
    #pragma unroll
    for (int j = 0; j < 4; ++j)
        #pragma unroll
        for (int i = 0; i < 4; ++i) acc[j][i] = 0.f;

    for (int s = 0; s < 128; ++s) {
        // prefetch step s+1 (wraps at end; last prefetch unused)
        int sn = (s + 1) & 127;
        int dkn4 = (sn & 3) << 4;                // d-chunk offset in float4 units
        int ktn  = (sn >> 2) << 6;
        float4 pA[4], pB[4];
        #pragma unroll
        for (int q = 0; q < 4; ++q) {
            int r = 16 * q + ty;
            pA[q] = x4[(size_t)(row0 + r) * 64 + dkn4 + tx];
            pB[q] = e4[(size_t)(ktn  + r) * 64 + dkn4 + tx];
        }

        // compute: acc[j][i] += x_row(j) . e_code(i) over this 64-dim chunk
        #pragma unroll
        for (int dd = 0; dd < BK; dd += 4) {
            float4 a[4], b[4];
            #pragma unroll
            for (int j = 0; j < 4; ++j) a[j] = *(const float4*)&As[ty + 16 * j][dd];
            #pragma unroll
            for (int i = 0; i < 4; ++i) b[i] = *(const float4*)&Bs[tx + 16 * i][dd];
            #pragma unroll
            for (int j = 0; j < 4; ++j)
                #pragma unroll
                for (int i = 0; i < 4; ++i)
                    acc[j][i] += a[j].x * b[i].x + a[j].y * b[i].y
                               + a[j].z * b[i].z + a[j].w * b[i].w;
        }

        if ((s & 3) == 3) {                      // full D done for this kt tile: fold argmin
            int kt = (s >> 2) << 6;
            #pragma unroll
            for (int i = 0; i < 4; ++i) {
                int k = kt + tx + 16 * i;        // ascending in i -> lowest-index tie win
                float ck = c[k];
                #pragma unroll
                for (int j = 0; j < 4; ++j) {
                    float t = x2r[j] + ck;               // matches reference eval order
                    float dst = t - 2.0f * acc[j][i];    // *2 exact
                    if (dst < best[j]) { best[j] = dst; bidx[j] = k; }
                }
            }
            #pragma unroll
            for (int j = 0; j < 4; ++j)
                #pragma unroll
                for (int i = 0; i < 4; ++i) acc[j][i] = 0.f;
        }

        __syncthreads();                         // all waves done reading this chunk
        if (s < 127) {
            #pragma unroll
            for (int q = 0; q < 4; ++q) {
                int r = 16 * q + ty;
                *(float4*)&As[r][tx << 2] = pA[q];
                *(float4*)&Bs[r][tx << 2] = pB[q];
            }
        }
        __syncthreads();                         // chunk s+1 visible
    }

    // final reduction: reuse As/Bs as redv/redi (all compute reads are behind the last barrier)
    float* redv = &As[0][0];                     // [64][16]
    int*   redi = (int*)&Bs[0][0];
    #pragma unroll
    for (int j = 0; j < 4; ++j) {
        int r = ty + 16 * j;
        redv[r * 16 + tx] = best[j];
        redi[r * 16 + tx] = bidx[j];
    }
    __syncthreads();
    if (tid < BM) {
        float bv = redv[tid * 16]; int bi = redi[tid * 16];
        for (int t = 1; t < 16; ++t) {
            float v = redv[tid * 16 + t]; int ii = redi[tid * 16 + t];
            if (v < bv || (v == bv && ii < bi)) { bv = v; bi = ii; }  // ties -> lowest index
        }
        int n = row0 + tid;
        idx_ws[n] = bi;
        idx_f[n] = (float)bi;
        atomicAdd(&counts[bi], 1u);
    }
}

// ---------------- gather: quantized_st = x + (e - x) (matches ST rounding), MSE sum ----------------
__global__ void vq_gather_kernel(const float* __restrict__ x, const float* __restrict__ emb,
                                 const int* __restrict__ idx, float* __restrict__ outq,
                                 double* __restrict__ sums) {
    __shared__ float red[256];
    int tid = threadIdx.x;
    int q = blockIdx.x * 256 + tid;        // float4 index, 4194304 total
    int n = q >> 6;
    int d4 = (q & 63) << 2;
    int k = idx[n];
    float4 e  = *(const float4*)(emb + (size_t)k * DIM + d4);
    float4 xv = *(const float4*)(x + ((size_t)n * DIM + d4));
    float d0 = e.x - xv.x, d1 = e.y - xv.y, d2 = e.z - xv.z, d3 = e.w - xv.w;
    float4 o;
    o.x = xv.x + d0; o.y = xv.y + d1; o.z = xv.z + d2; o.w = xv.w + d3;
    *(float4*)(outq + (size_t)q * 4) = o;
    red[tid] = d0 * d0 + d1 * d1 + d2 * d2 + d3 * d3;
    __syncthreads();
    for (int off = 128; off > 0; off >>= 1) {
        if (tid < off) red[tid] += red[tid + off];
        __syncthreads();
    }
    if (tid == 0) atomicAdd(&sums[0], (double)red[0]);
}

// ---------------- sim: sum |off-diagonal cosine| ----------------
#define SPAD 68
__global__ __launch_bounds__(256)
void vq_sim_kernel(const float* __restrict__ emb, const float* __restrict__ invn,
                   double* __restrict__ sums) {
    __shared__ float Ai[64][SPAD];
    __shared__ float Bj[64][SPAD];
    int bi = blockIdx.x >> 5;
    int bj = blockIdx.x & 31;
    int tid = threadIdx.x;
    int tx = tid & 15, ty = tid >> 4;

    float acc[4][4];
    #pragma unroll
    for (int j = 0; j < 4; ++j)
        #pragma unroll
        for (int i = 0; i < 4; ++i) acc[j][i] = 0.f;

    for (int dc = 0; dc < DIM; dc += 64) {
        #pragma unroll
        for (int rr = 0; rr < 4; ++rr) {
            int row = rr * 16 + ty;
            int col = tx * 4;
            int ga = bi * 64 + row, gb = bj * 64 + row;
            float4 a = *(const float4*)(emb + (size_t)ga * DIM + dc + col);
            float4 b = *(const float4*)(emb + (size_t)gb * DIM + dc + col);
            float sa = invn[ga], sb = invn[gb];
            Ai[row][col + 0] = a.x * sa; Ai[row][col + 1] = a.y * sa;
            Ai[row][col + 2] = a.z * sa; Ai[row][col + 3] = a.w * sa;
            Bj[row][col + 0] = b.x * sb; Bj[row][col + 1] = b.y * sb;
            Bj[row][col + 2] = b.z * sb; Bj[row][col + 3] = b.w * sb;
        }
        __syncthreads();
        for (int d = 0; d < 64; d += 4) {
            float4 a[4], b[4];
            #pragma unroll
            for (int j = 0; j < 4; ++j) a[j] = *(const float4*)&Ai[ty * 4 + j][d];
            #pragma unroll
            for (int i = 0; i < 4; ++i) b[i] = *(const float4*)&Bj[tx * 4 + i][d];
            #pragma unroll
            for (int j = 0; j < 4; ++j)
                #pragma unroll
                for (int i = 0; i < 4; ++i)
                    acc[j][i] += a[j].x * b[i].x + a[j].y * b[i].y
                               + a[j].z * b[i].z + a[j].w * b[i].w;
        }
        __syncthreads();
    }
    float s = 0.f;
    #pragma unroll
    for (int j = 0; j < 4; ++j)
        #pragma unroll
        for (int i = 0; i < 4; ++i) {
            int gi = bi * 64 + ty * 4 + j;
            int gj = bj * 64 + tx * 4 + i;
            if (gi != gj) s += fabsf(acc[j][i]);
        }
    float* red = &Ai[0][0];
    red[tid] = s;
    __syncthreads();
    for (int off = 128; off > 0; off >>= 1) {
        if (tid < off) red[tid] += red[tid + off];
        __syncthreads();
    }
    if (tid == 0) atomicAdd(&sums[2], (double)red[0]);
}

// ---------------- finalize: KL, perplexity, total loss ----------------
__global__ void vq_finalize_kernel(const unsigned* __restrict__ counts,
                                   const double* __restrict__ sums,
                                   float* __restrict__ out_scalars) {
    __shared__ double sred[256];
    int tid = threadIdx.x;
    double t = 0.0;
    for (int k = tid; k < KCODES; k += 256) t += (double)counts[k];
    sred[tid] = t; __syncthreads();
    for (int off = 128; off > 0; off >>= 1) {
        if (tid < off) sred[tid] += sred[tid + off];
        __syncthreads();
    }
    double total = sred[0];
    __syncthreads();

    const double eps = 1e-8, tunif = 1.0 / (double)KCODES;
    double klsum = 0.0, plogpsum = 0.0;
    for (int k = tid; k < KCODES; k += 256) {
        double p = (double)counts[k] / total;
        klsum += (p + eps) * log((p + eps) / (tunif + eps));
        if (p > 0.0) plogpsum += p * log(p);
    }
    sred[tid] = klsum; __syncthreads();
    for (int off = 128; off > 0; off >>= 1) {
        if (tid < off) sred[tid] += sred[tid + off];
        __syncthreads();
    }
    klsum = sred[0];
    __syncthreads();
    sred[tid] = plogpsum; __syncthreads();
    for (int off = 128; off > 0; off >>= 1) {
        if (tid < off) sred[tid] += sred[tid + off];
        __syncthreads();
    }
    plogpsum = sred[0];

    if (tid == 0) {
        float mse = (float)(sums[0] / (double)((size_t)NROWS * DIM));
        float vq = mse + 0.25f * mse;                       // q_latent + COST*e_latent (equal in value)
        float kl = fminf((float)klsum, 100.0f);
        float l2 = fminf((float)(sums[1] / (double)KCODES), 10.0f);
        float orth = fminf((float)(sums[2] / ((double)KCODES * (double)KCODES)), 10.0f);
        float reg = l2 + orth;
        float total_loss = fminf(vq + 0.1f * kl + 0.01f * reg, 100.0f);
        out_scalars[0] = total_loss;
        out_scalars[1] = (float)exp(-plogpsum);
    }
}

extern "C" void kernel_launch(void* const* d_in, const int* in_sizes, int n_in,
                              void* d_out, int out_size, void* d_ws, size_t ws_size,
                              hipStream_t stream) {
    const float* x   = (const float*)d_in[0];   // (16,4096,256) f32
    const float* emb = (const float*)d_in[1];   // (2048,256)   f32
    float* out = (float*)d_out;

    char* ws = (char*)d_ws;
    float*    c      = (float*)(ws + WS_C);
    float*    invn   = (float*)(ws + WS_INV);
    unsigned* counts = (unsigned*)(ws + WS_COUNTS);
    double*   sums   = (double*)(ws + WS_SUMS);
    int*      idx_ws = (int*)(ws + WS_IDX);

    float* outq        = out;                 // quantized_st
    float* out_scalars = out + Q_OFF;         // loss, perplexity
    float* idx_f       = out + Q_OFF + 2;     // idx as float

    vq_init_kernel<<<1, 256, 0, stream>>>(counts, sums);
    vq_prep_kernel<<<KCODES, 64, 0, stream>>>(emb, c, invn, sums);
    vq_argmin_kernel<<<NROWS / BM, 256, 0, stream>>>(x, emb, c, idx_ws, idx_f, counts);
    vq_gather_kernel<<<(NROWS * DIM / 4) / 256, 256, 0, stream>>>(x, emb, idx_ws, outq, sums);
    vq_sim_kernel<<<(KCODES / 64) * (KCODES / 64), 256, 0, stream>>>(emb, invn, sums);
    vq_finalize_kernel<<<1, 256, 0, stream>>>(counts, sums, out_scalars);
}